// Round 8
// baseline (1430.876 us; speedup 1.0000x reference)
//
#include <hip/hip_runtime.h>
#include <math.h>

constexpr int Bn = 16;
constexpr int Sn = 512;
constexpr int FCn = 24;
constexpr int FOn = 16;
constexpr int Dn = 512;
constexpr int Hn = 8;
constexpr int DKn = 64;
constexpr int FFn = 2048;
constexpr int Ln = 4;
constexpr int MAXPOSn = 512;
constexpr float EPSf = 1e-6f;

typedef __attribute__((ext_vector_type(8))) short bf16x8;   // 8 bf16 in 4 VGPRs
typedef __attribute__((ext_vector_type(4))) float floatx4;

__device__ __forceinline__ float sigmoidf_(float x) { return 1.0f / (1.0f + __expf(-x)); }

__device__ __forceinline__ unsigned short f2bf(float f) {  // RNE
  unsigned int u = __float_as_uint(f);
  u += 0x7fffu + ((u >> 16) & 1u);
  return (unsigned short)(u >> 16);
}
__device__ __forceinline__ float b2f(unsigned short b) {
  return __uint_as_float(((unsigned int)b) << 16);
}

__device__ __forceinline__ void g2l16(const void* g, void* l) {
  // async global->LDS, 16B/lane, LDS dest = wave-uniform base + lane*16
  __builtin_amdgcn_global_load_lds((const __attribute__((address_space(1))) void*)g,
                                   (__attribute__((address_space(3))) void*)l, 16, 0, 0);
}

// pair-pack bf16 store: even lane stores {self, lane^1} as one dword.
__device__ __forceinline__ void st_bf16_pair(unsigned short* dst, float v, int lane) {
  unsigned int us = f2bf(v);
  unsigned int other = (unsigned int)__shfl_xor((int)us, 1);
  if (!(lane & 1)) *(unsigned int*)dst = us | (other << 16);
}

__device__ __forceinline__ float waveReduceSum(float v) {
  #pragma unroll
  for (int off = 32; off >= 1; off >>= 1) v += __shfl_xor(v, off);
  return v;
}

__device__ __forceinline__ float blockReduceSum(float v) {
  v = waveReduceSum(v);
  __shared__ float red[8];
  const int w = threadIdx.x >> 6;
  const int nw = blockDim.x >> 6;
  if ((threadIdx.x & 63) == 0) red[w] = v;
  __syncthreads();
  float r = 0.0f;
  for (int i = 0; i < nw; ++i) r += red[i];
  __syncthreads();
  return r;
}

// ---------- weight transpose-convert: out[n][k] bf16 = in[k][n] f32 ----------
__global__ __launch_bounds__(256) void wconv_kernel(
    const float* __restrict__ in, unsigned short* __restrict__ out,
    int K, int N, size_t inStride, size_t outStride) {
  __shared__ float tile[32][33];
  in += (size_t)blockIdx.z * inStride;
  out += (size_t)blockIdx.z * outStride;
  const int k0 = blockIdx.y * 32, n0 = blockIdx.x * 32;
  const int tr = threadIdx.x >> 3;         // 0..31
  const int tc4 = (threadIdx.x & 7) * 4;   // 0..28
  float4 vv = *(const float4*)&in[(size_t)(k0 + tr) * N + n0 + tc4];
  tile[tr][tc4 + 0] = vv.x; tile[tr][tc4 + 1] = vv.y;
  tile[tr][tc4 + 2] = vv.z; tile[tr][tc4 + 3] = vv.w;
  __syncthreads();
  ushort4 o4;
  o4.x = f2bf(tile[tc4 + 0][tr]); o4.y = f2bf(tile[tc4 + 1][tr]);
  o4.z = f2bf(tile[tc4 + 2][tr]); o4.w = f2bf(tile[tc4 + 3][tr]);
  *(ushort4*)&out[(size_t)(n0 + tr) * K + k0 + tc4] = o4;
}

// bias concat: [L][2048] = [bq|bk|bv|bg]
__global__ void bcat_kernel(const float* __restrict__ bq, const float* __restrict__ bk,
                            const float* __restrict__ bv, const float* __restrict__ bg,
                            float* __restrict__ out) {
  const int t = blockIdx.x * 256 + threadIdx.x;  // 8192
  const int l = t >> 11;
  const int c = t & 2047;
  float v;
  if (c < 512) v = bq[l * 512 + c];
  else if (c < 1024) v = bk[l * 512 + c - 512];
  else if (c < 1536) v = bv[l * 512 + c - 1024];
  else v = bg[l * 512 + c - 1536];
  out[t] = v;
}

// x = x_cgm @ cgm_W + cgm_b  -> fp32 X and bf16 Xb
__global__ __launch_bounds__(256) void embed_kernel(
    const float* __restrict__ xc, const float* __restrict__ W,
    const float* __restrict__ bias, float* __restrict__ x,
    unsigned short* __restrict__ xb) {
  const int idx = blockIdx.x * 256 + threadIdx.x;
  const int n = idx & (Dn - 1);
  const int m = idx >> 9;
  const float* xr = xc + m * FCn;
  float acc = bias[n];
  #pragma unroll
  for (int k = 0; k < FCn; ++k) acc = fmaf(xr[k], W[k * Dn + n], acc);
  x[idx] = acc;
  xb[idx] = f2bf(acc);
}

__global__ void relmean_kernel(const float* __restrict__ rel, float* __restrict__ rm) {
  const int p = blockIdx.x * blockDim.x + threadIdx.x;
  if (p >= 2 * MAXPOSn - 1) return;
  float s = 0.0f;
  #pragma unroll 8
  for (int d = 0; d < DKn; ++d) s += rel[p * DKn + d];
  rm[p] = s * (1.0f / DKn);
}

// ---------- gemm256: C = A[M,K] @ Bt[N,K]^T + bias, qkvg epilogue ----------
// Block 256m x 128n, BK=32; 4 waves each 128m x 64n (acc 8x4 floatx4 = 128 AGPR).
// 32 MFMA per 12 ds_read_b128 per wave-iter (0.375 reads/MFMA vs 0.5 in the
// 64x64-wave version) — LDS BW drops below the MFMA floor.
// EPI: 4 = qkvg split (cols<1536 -> bf16 Cb ld1536; else sigmoid bf16 Cb2 ld512)
template <int EPI>
__global__ __launch_bounds__(256) void gemm256(
    const unsigned short* __restrict__ A, const unsigned short* __restrict__ Bt,
    const float* __restrict__ bias, unsigned short* __restrict__ Cb,
    unsigned short* __restrict__ Cb2, int Astride, int Klen, int nt) {
  __shared__ unsigned short As[256 * 32];  // 16 KB
  __shared__ unsigned short Bs[128 * 32];  // 8 KB
  const int t = threadIdx.x;
  const int w = t >> 6;
  const int lane = t & 63;
  const int id = blockIdx.x;
  const int xcd = id & 7;
  const int lid = id >> 3;
  const int n0 = (lid % nt) * 128;
  const int m0 = (xcd * 4 + lid / nt) * 256;
  const int wm = (w >> 1) * 128;
  const int wn = (w & 1) * 64;
  const int lr = lane & 15;
  const int lq = lane >> 4;

  floatx4 acc[8][4];
  #pragma unroll
  for (int i = 0; i < 8; ++i)
    #pragma unroll
    for (int j = 0; j < 4; ++j) acc[i][j] = (floatx4){0.f, 0.f, 0.f, 0.f};

  const int srow = lane >> 2;   // 0..15
  const int schk = (lane & 3) * 8;

  for (int k0 = 0; k0 < Klen; k0 += 32) {
    __syncthreads();
    #pragma unroll
    for (int r = 0; r < 4; ++r) {
      const int rb = (w * 4 + r) * 16;
      g2l16(&A[(size_t)(m0 + rb + srow) * Astride + k0 + schk], &As[rb * 32]);
    }
    #pragma unroll
    for (int r = 0; r < 2; ++r) {
      const int rb = (w * 2 + r) * 16;
      g2l16(&Bt[(size_t)(n0 + rb + srow) * Astride + k0 + schk], &Bs[rb * 32]);
    }
    __syncthreads();
    bf16x8 af[8], bf[4];
    #pragma unroll
    for (int i = 0; i < 8; ++i)
      af[i] = *(const bf16x8*)&As[(wm + i * 16 + lr) * 32 + lq * 8];
    #pragma unroll
    for (int j = 0; j < 4; ++j)
      bf[j] = *(const bf16x8*)&Bs[(wn + j * 16 + lr) * 32 + lq * 8];
    #pragma unroll
    for (int i = 0; i < 8; ++i)
      #pragma unroll
      for (int j = 0; j < 4; ++j)
        acc[i][j] = __builtin_amdgcn_mfma_f32_16x16x32_bf16(af[i], bf[j], acc[i][j], 0, 0, 0);
  }

  // C/D layout: col = lane&15, row = (lane>>4)*4 + reg
  #pragma unroll
  for (int i = 0; i < 8; ++i) {
    const int row = m0 + wm + i * 16 + lq * 4;
    #pragma unroll
    for (int j = 0; j < 4; ++j) {
      const int col = n0 + wn + j * 16 + lr;
      const int colp = col & ~1;
      #pragma unroll
      for (int r = 0; r < 4; ++r) {
        const float va = acc[i][j][r] + bias[col];
        if (EPI == 4) {
          if (col < 1536)
            st_bf16_pair(&Cb[(size_t)(row + r) * 1536 + colp], va, lane);
          else
            st_bf16_pair(&Cb2[(size_t)(row + r) * 512 + (colp - 1536)], sigmoidf_(va), lane);
        } else {
          st_bf16_pair(&Cb[(size_t)(row + r) * nt * 128 + colp], va, lane);
        }
      }
    }
  }
}

// ---------- ff256: C = (A@W1+b1) * sigmoid(A@W2+b2), bf16 out ----------
// Block 256m x 64n-pair; 4 waves each 128m x 32n-pair (a1/a2 8x2 = 128 AGPR).
// 32 MFMA per 12 reads per wave-iter.
__global__ __launch_bounds__(256) void ff256(
    const unsigned short* __restrict__ A, const unsigned short* __restrict__ B1t,
    const unsigned short* __restrict__ B2t, const float* __restrict__ b1,
    const float* __restrict__ b2, unsigned short* __restrict__ C, int K) {
  __shared__ unsigned short As[256 * 32];  // 16 KB
  __shared__ unsigned short B1s[64 * 32];  // 4 KB
  __shared__ unsigned short B2s[64 * 32];  // 4 KB
  const int t = threadIdx.x;
  const int w = t >> 6;
  const int lane = t & 63;
  const int id = blockIdx.x;
  const int xcd = id & 7;
  const int lid = id >> 3;            // 0..127
  const int n0 = (lid & 31) * 64;
  const int m0 = (xcd * 4 + (lid >> 5)) * 256;
  const int wm = (w >> 1) * 128;
  const int wn = (w & 1) * 32;
  const int lr = lane & 15;
  const int lq = lane >> 4;

  floatx4 a1[8][2], a2[8][2];
  #pragma unroll
  for (int i = 0; i < 8; ++i)
    #pragma unroll
    for (int j = 0; j < 2; ++j) {
      a1[i][j] = (floatx4){0.f, 0.f, 0.f, 0.f};
      a2[i][j] = (floatx4){0.f, 0.f, 0.f, 0.f};
    }

  const int srow = lane >> 2;
  const int schk = (lane & 3) * 8;

  for (int k0 = 0; k0 < K; k0 += 32) {
    __syncthreads();
    #pragma unroll
    for (int r = 0; r < 4; ++r) {
      const int rb = (w * 4 + r) * 16;
      g2l16(&A[(size_t)(m0 + rb + srow) * K + k0 + schk], &As[rb * 32]);
    }
    g2l16(&B1t[(size_t)(n0 + w * 16 + srow) * K + k0 + schk], &B1s[(w * 16) * 32]);
    g2l16(&B2t[(size_t)(n0 + w * 16 + srow) * K + k0 + schk], &B2s[(w * 16) * 32]);
    __syncthreads();
    bf16x8 af[8], f1[2], f2[2];
    #pragma unroll
    for (int i = 0; i < 8; ++i)
      af[i] = *(const bf16x8*)&As[(wm + i * 16 + lr) * 32 + lq * 8];
    #pragma unroll
    for (int j = 0; j < 2; ++j) {
      f1[j] = *(const bf16x8*)&B1s[(wn + j * 16 + lr) * 32 + lq * 8];
      f2[j] = *(const bf16x8*)&B2s[(wn + j * 16 + lr) * 32 + lq * 8];
    }
    #pragma unroll
    for (int i = 0; i < 8; ++i)
      #pragma unroll
      for (int j = 0; j < 2; ++j) {
        a1[i][j] = __builtin_amdgcn_mfma_f32_16x16x32_bf16(af[i], f1[j], a1[i][j], 0, 0, 0);
        a2[i][j] = __builtin_amdgcn_mfma_f32_16x16x32_bf16(af[i], f2[j], a2[i][j], 0, 0, 0);
      }
  }

  #pragma unroll
  for (int i = 0; i < 8; ++i) {
    const int row = m0 + wm + i * 16 + lq * 4;
    #pragma unroll
    for (int j = 0; j < 2; ++j) {
      const int col = n0 + wn + j * 16 + lr;
      const int colp = col & ~1;
      const float bb1 = b1[col], bb2 = b2[col];
      #pragma unroll
      for (int r = 0; r < 4; ++r) {
        const float f = (a1[i][j][r] + bb1) * sigmoidf_(a2[i][j][r] + bb2);
        st_bf16_pair(&C[(size_t)(row + r) * 2048 + colp], f, lane);
      }
    }
  }
}

// ---------- bf16 MFMA GEMM, 128m x 64n tile (N=512: Wo, Wf2) ----------
// Grid 512 = 2 blocks/CU, full-K. EPI: 0 fp32 +bias; 3 bf16 +bias.
template <int EPI>
__global__ __launch_bounds__(256) void mgemm_n64(
    const unsigned short* __restrict__ A, const unsigned short* __restrict__ Bt,
    const float* __restrict__ bias, float* __restrict__ Cf,
    unsigned short* __restrict__ Cb, int Astride, int Klen, int ldc) {
  __shared__ unsigned short As[128 * 32];
  __shared__ unsigned short Bs[64 * 32];
  const int t = threadIdx.x;
  const int w = t >> 6;
  const int lane = t & 63;
  const int id = blockIdx.x;
  const int xcd = id & 7;
  const int lid = id >> 3;               // 0..63
  const int n0 = (lid & 7) * 64;         // 8 n-tiles
  const int m0 = (xcd * 8 + (lid >> 3)) * 128;
  const int wm = (w >> 1) * 64;
  const int wn = (w & 1) * 32;
  const int lr = lane & 15;
  const int lq = lane >> 4;

  floatx4 acc[4][2];
  #pragma unroll
  for (int i = 0; i < 4; ++i)
    #pragma unroll
    for (int j = 0; j < 2; ++j) acc[i][j] = (floatx4){0.f, 0.f, 0.f, 0.f};

  const int srow = lane >> 2;
  const int schk = (lane & 3) * 8;

  for (int k0 = 0; k0 < Klen; k0 += 32) {
    __syncthreads();
    #pragma unroll
    for (int r = 0; r < 2; ++r) {
      const int rb = (w * 2 + r) * 16;
      g2l16(&A[(size_t)(m0 + rb + srow) * Astride + k0 + schk], &As[rb * 32]);
    }
    g2l16(&Bt[(size_t)(n0 + w * 16 + srow) * Astride + k0 + schk], &Bs[(w * 16) * 32]);
    __syncthreads();
    bf16x8 af[4], bf[2];
    #pragma unroll
    for (int i = 0; i < 4; ++i)
      af[i] = *(const bf16x8*)&As[(wm + i * 16 + lr) * 32 + lq * 8];
    #pragma unroll
    for (int j = 0; j < 2; ++j)
      bf[j] = *(const bf16x8*)&Bs[(wn + j * 16 + lr) * 32 + lq * 8];
    #pragma unroll
    for (int i = 0; i < 4; ++i)
      #pragma unroll
      for (int j = 0; j < 2; ++j)
        acc[i][j] = __builtin_amdgcn_mfma_f32_16x16x32_bf16(af[i], bf[j], acc[i][j], 0, 0, 0);
  }

  #pragma unroll
  for (int i = 0; i < 4; ++i) {
    const int row = m0 + wm + i * 16 + lq * 4;
    #pragma unroll
    for (int j = 0; j < 2; ++j) {
      const int col = n0 + wn + j * 16 + lr;
      const int colp = col & ~1;
      const float bv = bias[col];
      #pragma unroll
      for (int r = 0; r < 4; ++r) {
        if (EPI == 0) {
          Cf[(size_t)(row + r) * ldc + col] = acc[i][j][r] + bv;
        } else {
          st_bf16_pair(&Cb[(size_t)(row + r) * ldc + colp], acc[i][j][r] + bv, lane);
        }
      }
    }
  }
}

// ---------- MFMA flash attention ----------
__global__ __launch_bounds__(256) void attn_kernel(
    const unsigned short* __restrict__ qkv, const float* __restrict__ rm,
    unsigned short* __restrict__ ctx) {
  __shared__ unsigned short Ks[64 * 72];
  __shared__ unsigned short Vt[64 * 72];
  __shared__ unsigned short Pw[4][16 * 72];
  __shared__ float rml[576];
  const int t = threadIdx.x;
  const int w = t >> 6;
  const int lane = t & 63;
  const int lr = lane & 15;
  const int lq = lane >> 4;
  const int bid = blockIdx.x;
  const int b = bid & 15;
  const int h = (bid >> 4) & 7;
  const int qt = bid >> 7;
  const int q0 = qt * 64;
  const size_t rowb = (size_t)b * Sn * 1536;

  for (int i = t; i < 576; i += 256) rml[i] = rm[q0 + i];

  bf16x8 aq0, aq1;
  {
    const unsigned short* qp = &qkv[rowb + (size_t)(q0 + w * 16 + lr) * 1536 + h * 64 + lq * 8];
    aq0 = *(const bf16x8*)qp;
    aq1 = *(const bf16x8*)(qp + 32);
  }

  floatx4 o_acc[4];
  #pragma unroll
  for (int i = 0; i < 4; ++i) o_acc[i] = (floatx4){0.f, 0.f, 0.f, 0.f};
  float m_old[4] = {-1e30f, -1e30f, -1e30f, -1e30f};
  float l_sum[4] = {0.f, 0.f, 0.f, 0.f};

  const int skey = t >> 2;
  const int schk = (t & 3) * 16;
  const int vkp = t >> 4;
  const int vd4 = (t & 15) * 4;

  for (int kc = 0; kc < 8; ++kc) {
    __syncthreads();
    {
      const unsigned short* gk = &qkv[rowb + (size_t)(kc * 64 + skey) * 1536 + 512 + h * 64 + schk];
      *(bf16x8*)&Ks[skey * 72 + schk] = *(const bf16x8*)gk;
      *(bf16x8*)&Ks[skey * 72 + schk + 8] = *(const bf16x8*)(gk + 8);
    }
    #pragma unroll
    for (int pass = 0; pass < 2; ++pass) {
      const int kp = vkp + pass * 16;
      const unsigned short* gv = &qkv[rowb + (size_t)(kc * 64 + kp * 2) * 1536 + 1024 + h * 64 + vd4];
      ushort4 v0 = *(const ushort4*)gv;
      ushort4 v1 = *(const ushort4*)(gv + 1536);
      *(ushort2*)&Vt[(vd4 + 0) * 72 + kp * 2] = make_ushort2(v0.x, v1.x);
      *(ushort2*)&Vt[(vd4 + 1) * 72 + kp * 2] = make_ushort2(v0.y, v1.y);
      *(ushort2*)&Vt[(vd4 + 2) * 72 + kp * 2] = make_ushort2(v0.z, v1.z);
      *(ushort2*)&Vt[(vd4 + 3) * 72 + kp * 2] = make_ushort2(v0.w, v1.w);
    }
    __syncthreads();

    floatx4 s_acc[4];
    #pragma unroll
    for (int j = 0; j < 4; ++j) {
      bf16x8 b0 = *(const bf16x8*)&Ks[(j * 16 + lr) * 72 + lq * 8];
      bf16x8 b1 = *(const bf16x8*)&Ks[(j * 16 + lr) * 72 + 32 + lq * 8];
      s_acc[j] = __builtin_amdgcn_mfma_f32_16x16x32_bf16(aq0, b0, (floatx4){0.f, 0.f, 0.f, 0.f}, 0, 0, 0);
      s_acc[j] = __builtin_amdgcn_mfma_f32_16x16x32_bf16(aq1, b1, s_acc[j], 0, 0, 0);
    }

    float mloc[4] = {-1e30f, -1e30f, -1e30f, -1e30f};
    #pragma unroll
    for (int j = 0; j < 4; ++j) {
      const int key = kc * 64 + j * 16 + lr;
      #pragma unroll
      for (int r = 0; r < 4; ++r) {
        const float sv = s_acc[j][r] * 0.125f + rml[(w * 16 + lq * 4 + r) + 511 - key];
        s_acc[j][r] = sv;
        mloc[r] = fmaxf(mloc[r], sv);
      }
    }
    #pragma unroll
    for (int off = 1; off <= 8; off <<= 1)
      #pragma unroll
      for (int r = 0; r < 4; ++r) mloc[r] = fmaxf(mloc[r], __shfl_xor(mloc[r], off));

    float alpha[4], rsum[4];
    #pragma unroll
    for (int r = 0; r < 4; ++r) {
      const float mnew = fmaxf(m_old[r], mloc[r]);
      alpha[r] = __expf(m_old[r] - mnew);
      m_old[r] = mnew;
      rsum[r] = 0.f;
    }
    #pragma unroll
    for (int j = 0; j < 4; ++j)
      #pragma unroll
      for (int r = 0; r < 4; ++r) {
        const float p = __expf(s_acc[j][r] - m_old[r]);
        rsum[r] += p;
        Pw[w][(lq * 4 + r) * 72 + j * 16 + lr] = f2bf(p);
      }
    #pragma unroll
    for (int off = 1; off <= 8; off <<= 1)
      #pragma unroll
      for (int r = 0; r < 4; ++r) rsum[r] += __shfl_xor(rsum[r], off);
    #pragma unroll
    for (int r = 0; r < 4; ++r) l_sum[r] = l_sum[r] * alpha[r] + rsum[r];
    #pragma unroll
    for (int i = 0; i < 4; ++i)
      #pragma unroll
      for (int r = 0; r < 4; ++r) o_acc[i][r] *= alpha[r];

    bf16x8 ap0 = *(const bf16x8*)&Pw[w][lr * 72 + lq * 8];
    bf16x8 ap1 = *(const bf16x8*)&Pw[w][lr * 72 + 32 + lq * 8];
    #pragma unroll
    for (int i = 0; i < 4; ++i) {
      bf16x8 v0 = *(const bf16x8*)&Vt[(i * 16 + lr) * 72 + lq * 8];
      bf16x8 v1 = *(const bf16x8*)&Vt[(i * 16 + lr) * 72 + 32 + lq * 8];
      o_acc[i] = __builtin_amdgcn_mfma_f32_16x16x32_bf16(ap0, v0, o_acc[i], 0, 0, 0);
      o_acc[i] = __builtin_amdgcn_mfma_f32_16x16x32_bf16(ap1, v1, o_acc[i], 0, 0, 0);
    }
  }

  float rinv[4];
  #pragma unroll
  for (int r = 0; r < 4; ++r) rinv[r] = 1.0f / l_sum[r];
  #pragma unroll
  for (int i = 0; i < 4; ++i)
    #pragma unroll
    for (int r = 0; r < 4; ++r) {
      const int q = q0 + w * 16 + lq * 4 + r;
      ctx[((size_t)(b * Sn + q)) * Dn + h * 64 + i * 16 + lr] = f2bf(o_acc[i][r] * rinv[r]);
    }
}

// ---------- wave-per-row LN (no barriers): 4 rows/block ----------
__global__ __launch_bounds__(256) void ln_res1_kernel(
    float* __restrict__ x, unsigned short* __restrict__ xb,
    const unsigned short* __restrict__ att, const unsigned short* __restrict__ gate,
    const float* __restrict__ s, const float* __restrict__ bsh) {
  const int w = threadIdx.x >> 6, lane = threadIdx.x & 63;
  const int row = blockIdx.x * 4 + w;
  const size_t base = (size_t)row * Dn;
  const int c = lane * 4;
  float4 xv0 = *(const float4*)&x[base + c];
  float4 xv1 = *(const float4*)&x[base + c + 256];
  ushort4 a0 = *(const ushort4*)&att[base + c];
  ushort4 a1 = *(const ushort4*)&att[base + c + 256];
  ushort4 g0 = *(const ushort4*)&gate[base + c];
  ushort4 g1 = *(const ushort4*)&gate[base + c + 256];
  float y[8];
  y[0] = xv0.x + b2f(a0.x) * b2f(g0.x);
  y[1] = xv0.y + b2f(a0.y) * b2f(g0.y);
  y[2] = xv0.z + b2f(a0.z) * b2f(g0.z);
  y[3] = xv0.w + b2f(a0.w) * b2f(g0.w);
  y[4] = xv1.x + b2f(a1.x) * b2f(g1.x);
  y[5] = xv1.y + b2f(a1.y) * b2f(g1.y);
  y[6] = xv1.z + b2f(a1.z) * b2f(g1.z);
  y[7] = xv1.w + b2f(a1.w) * b2f(g1.w);
  float sum = 0.f;
  #pragma unroll
  for (int i = 0; i < 8; ++i) sum += y[i];
  const float mu = waveReduceSum(sum) * (1.0f / Dn);
  float vs = 0.f;
  #pragma unroll
  for (int i = 0; i < 8; ++i) { y[i] -= mu; vs += y[i] * y[i]; }
  const float rstd = rsqrtf(waveReduceSum(vs) * (1.0f / Dn) + EPSf);
  float4 s0 = *(const float4*)&s[c], s1 = *(const float4*)&s[c + 256];
  float4 b0 = *(const float4*)&bsh[c], b1 = *(const float4*)&bsh[c + 256];
  float4 o0, o1;
  o0.x = y[0] * rstd * s0.x + b0.x; o0.y = y[1] * rstd * s0.y + b0.y;
  o0.z = y[2] * rstd * s0.z + b0.z; o0.w = y[3] * rstd * s0.w + b0.w;
  o1.x = y[4] * rstd * s1.x + b1.x; o1.y = y[5] * rstd * s1.y + b1.y;
  o1.z = y[6] * rstd * s1.z + b1.z; o1.w = y[7] * rstd * s1.w + b1.w;
  *(float4*)&x[base + c] = o0;
  *(float4*)&x[base + c + 256] = o1;
  ushort4 ob0, ob1;
  ob0.x = f2bf(o0.x); ob0.y = f2bf(o0.y); ob0.z = f2bf(o0.z); ob0.w = f2bf(o0.w);
  ob1.x = f2bf(o1.x); ob1.y = f2bf(o1.y); ob1.z = f2bf(o1.z); ob1.w = f2bf(o1.w);
  *(ushort4*)&xb[base + c] = ob0;
  *(ushort4*)&xb[base + c + 256] = ob1;
}

__global__ __launch_bounds__(256) void ln_res2_kernel(
    float* __restrict__ x, unsigned short* __restrict__ xb,
    const float* __restrict__ add, const float* __restrict__ s,
    const float* __restrict__ bsh) {
  const int w = threadIdx.x >> 6, lane = threadIdx.x & 63;
  const int row = blockIdx.x * 4 + w;
  const size_t base = (size_t)row * Dn;
  const int c = lane * 4;
  float4 xv0 = *(const float4*)&x[base + c];
  float4 xv1 = *(const float4*)&x[base + c + 256];
  float4 a0 = *(const float4*)&add[base + c];
  float4 a1 = *(const float4*)&add[base + c + 256];
  float y[8] = {xv0.x + a0.x, xv0.y + a0.y, xv0.z + a0.z, xv0.w + a0.w,
                xv1.x + a1.x, xv1.y + a1.y, xv1.z + a1.z, xv1.w + a1.w};
  float sum = 0.f;
  #pragma unroll
  for (int i = 0; i < 8; ++i) sum += y[i];
  const float mu = waveReduceSum(sum) * (1.0f / Dn);
  float vs = 0.f;
  #pragma unroll
  for (int i = 0; i < 8; ++i) { y[i] -= mu; vs += y[i] * y[i]; }
  const float rstd = rsqrtf(waveReduceSum(vs) * (1.0f / Dn) + EPSf);
  float4 s0 = *(const float4*)&s[c], s1 = *(const float4*)&s[c + 256];
  float4 b0 = *(const float4*)&bsh[c], b1 = *(const float4*)&bsh[c + 256];
  float4 o0, o1;
  o0.x = y[0] * rstd * s0.x + b0.x; o0.y = y[1] * rstd * s0.y + b0.y;
  o0.z = y[2] * rstd * s0.z + b0.z; o0.w = y[3] * rstd * s0.w + b0.w;
  o1.x = y[4] * rstd * s1.x + b1.x; o1.y = y[5] * rstd * s1.y + b1.y;
  o1.z = y[6] * rstd * s1.z + b1.z; o1.w = y[7] * rstd * s1.w + b1.w;
  *(float4*)&x[base + c] = o0;
  *(float4*)&x[base + c + 256] = o1;
  ushort4 ob0, ob1;
  ob0.x = f2bf(o0.x); ob0.y = f2bf(o0.y); ob0.z = f2bf(o0.z); ob0.w = f2bf(o0.w);
  ob1.x = f2bf(o1.x); ob1.y = f2bf(o1.y); ob1.z = f2bf(o1.z); ob1.w = f2bf(o1.w);
  *(ushort4*)&xb[base + c] = ob0;
  *(ushort4*)&xb[base + c + 256] = ob1;
}

// meanpool partial: block (b, sc) sums 64 rows -> part[b][sc][512]
__global__ __launch_bounds__(256) void mp_part_kernel(const float* __restrict__ x,
                                                      float* __restrict__ part) {
  const int b = blockIdx.x, sc = blockIdx.y;
  const int t = threadIdx.x;
  float s0 = 0.f, s1 = 0.f;
  for (int si = sc * 64; si < sc * 64 + 64; ++si) {
    s0 += x[((size_t)(b * Sn + si)) * Dn + t];
    s1 += x[((size_t)(b * Sn + si)) * Dn + t + 256];
  }
  part[(size_t)(b * 8 + sc) * 512 + t] = s0;
  part[(size_t)(b * 8 + sc) * 512 + t + 256] = s1;
}

// combine + xo: h[b][0:512] = mean, h[b][512:1024] = x_other@W+b
__global__ __launch_bounds__(256) void mp_comb_xo_kernel(
    const float* __restrict__ part, const float* __restrict__ xo,
    const float* __restrict__ oW, const float* __restrict__ ob,
    float* __restrict__ h) {
  const int idx = blockIdx.x * 256 + threadIdx.x;  // 8192
  const int b = idx >> 9, d = idx & 511;
  float s = 0.f;
  #pragma unroll
  for (int i = 0; i < 8; ++i) s += part[(size_t)(b * 8 + i) * 512 + d];
  h[b * 1024 + d] = s * (1.0f / Sn);
  float acc = ob[d];
  #pragma unroll
  for (int k = 0; k < FOn; ++k) acc = fmaf(xo[b * FOn + k], oW[k * Dn + d], acc);
  h[b * 1024 + 512 + d] = acc;
}

// f1 phase A: part[b][kq][n] = sum_{k in slice} h[b][k] * W[k][n]   (grid 16x8)
__global__ __launch_bounds__(256) void f1a_kernel(
    const float* __restrict__ h, const float* __restrict__ W,
    float* __restrict__ part) {
  const int b = blockIdx.x, kq = blockIdx.y;
  const int n = threadIdx.x;  // 256
  const float* hr = h + b * 1024 + kq * 128;
  const float* Wp = W + (size_t)(kq * 128) * 256 + n;
  float acc = 0.f;
  #pragma unroll 8
  for (int k = 0; k < 128; ++k) acc = fmaf(hr[k], Wp[(size_t)k * 256], acc);
  part[(size_t)(b * 8 + kq) * 256 + n] = acc;
}

// tail: f1b (sum partials + LN256 + relu) -> f2 (GEMV + LN128 + relu) -> f3 (dot)
__global__ __launch_bounds__(256) void tail_kernel(
    const float* __restrict__ part, const float* __restrict__ fb1,
    const float* __restrict__ fln1_s, const float* __restrict__ fln1_b,
    const float* __restrict__ fW2, const float* __restrict__ fb2,
    const float* __restrict__ fln2_s, const float* __restrict__ fln2_b,
    const float* __restrict__ fW3, const float* __restrict__ fb3,
    float* __restrict__ out) {
  __shared__ float h1[256];
  const int b = blockIdx.x;
  const int t = threadIdx.x;  // 256
  float acc = fb1[t];
  #pragma unroll
  for (int i = 0; i < 8; ++i) acc += part[(size_t)(b * 8 + i) * 256 + t];
  float mu = blockReduceSum(acc) * (1.0f / 256.0f);
  float d = acc - mu;
  float var = blockReduceSum(d * d) * (1.0f / 256.0f);
  h1[t] = fmaxf(d * rsqrtf(var + EPSf) * fln1_s[t] + fln1_b[t], 0.0f);
  __syncthreads();
  float acc2 = 0.f;
  if (t < 128) {
    #pragma unroll 8
    for (int k = 0; k < 256; ++k) acc2 = fmaf(h1[k], fW2[k * 128 + t], acc2);
    acc2 += fb2[t];
  }
  mu = blockReduceSum(t < 128 ? acc2 : 0.f) * (1.0f / 128.0f);
  d = (t < 128) ? acc2 - mu : 0.f;
  var = blockReduceSum(d * d) * (1.0f / 128.0f);
  float v = 0.f;
  if (t < 128) {
    const float h2v = fmaxf(d * rsqrtf(var + EPSf) * fln2_s[t] + fln2_b[t], 0.0f);
    v = h2v * fW3[t];
  }
  v = blockReduceSum(v);
  if (t == 0) out[b] = v + fb3[0];
}

extern "C" void kernel_launch(void* const* d_in, const int* in_sizes, int n_in,
                              void* d_out, int out_size, void* d_ws, size_t ws_size,
                              hipStream_t stream) {
  (void)in_sizes; (void)n_in; (void)out_size; (void)ws_size;
  const float* x_cgm  = (const float*)d_in[0];
  const float* x_other= (const float*)d_in[1];
  const float* cgm_W  = (const float*)d_in[2];
  const float* cgm_b  = (const float*)d_in[3];
  const float* rel_emb= (const float*)d_in[4];
  const float* Wq = (const float*)d_in[5];
  const float* bq = (const float*)d_in[6];
  const float* Wk = (const float*)d_in[7];
  const float* bk = (const float*)d_in[8];
  const float* Wv = (const float*)d_in[9];
  const float* bv = (const float*)d_in[10];
  const float* Wo = (const float*)d_in[11];
  const float* bo = (const float*)d_in[12];
  const float* Wg = (const float*)d_in[13];
  const float* bg = (const float*)d_in[14];
  const float* Wf1 = (const float*)d_in[15];
  const float* bf1 = (const float*)d_in[16];
  const float* Wfg = (const float*)d_in[17];
  const float* bfg = (const float*)d_in[18];
  const float* Wf2 = (const float*)d_in[19];
  const float* bf2 = (const float*)d_in[20];
  const float* ln1_s = (const float*)d_in[21];
  const float* ln1_b = (const float*)d_in[22];
  const float* ln2_s = (const float*)d_in[23];
  const float* ln2_b = (const float*)d_in[24];
  const float* other_W = (const float*)d_in[25];
  const float* other_b = (const float*)d_in[26];
  const float* fW1 = (const float*)d_in[27];
  const float* fb1 = (const float*)d_in[28];
  const float* fln1_s = (const float*)d_in[29];
  const float* fln1_b = (const float*)d_in[30];
  const float* fW2 = (const float*)d_in[31];
  const float* fb2 = (const float*)d_in[32];
  const float* fln2_s = (const float*)d_in[33];
  const float* fln2_b = (const float*)d_in[34];
  const float* fW3 = (const float*)d_in[35];
  const float* fb3 = (const float*)d_in[36];
  float* out = (float*)d_out;

  char* p = (char*)d_ws;
  auto alloc = [&](size_t bytes) { char* r = p; p += (bytes + 255) & ~(size_t)255; return r; };
  float*          X      = (float*)alloc((size_t)8192 * 512 * 4);
  unsigned short* Xb     = (unsigned short*)alloc((size_t)8192 * 512 * 2);
  unsigned short* QKVb   = (unsigned short*)alloc((size_t)8192 * 1536 * 2);  // also CTXo f32
  unsigned short* CTXb   = (unsigned short*)alloc((size_t)8192 * 512 * 2);
  char*           R      = alloc((size_t)8192 * 2048 * 2);  // ATTb|GATEb bf16 / FFBh overlay
  unsigned short* ATTb   = (unsigned short*)R;
  unsigned short* GATEb  = (unsigned short*)(R + (size_t)8192 * 512 * 2);
  unsigned short* FFBh   = (unsigned short*)R;               // [8192][2048] bf16
  float*          CTXo   = (float*)QKVb;
  unsigned short* Wqkvgt = (unsigned short*)alloc((size_t)4 * 2048 * 512 * 2);
  unsigned short* Wot    = (unsigned short*)alloc((size_t)4 * 512 * 512 * 2);
  unsigned short* Wf1t   = (unsigned short*)alloc((size_t)4 * 2048 * 512 * 2);
  unsigned short* Wfgt   = (unsigned short*)alloc((size_t)4 * 2048 * 512 * 2);
  unsigned short* Wf2t   = (unsigned short*)alloc((size_t)4 * 512 * 2048 * 2);
  float*          bqkvg  = (float*)alloc((size_t)4 * 2048 * 4);
  float*          RMb    = (float*)alloc(1024 * 4);
  float*          Hb     = (float*)alloc(16 * 1024 * 4);
  float*          MPP    = (float*)alloc((size_t)16 * 8 * 512 * 4);
  float*          F1P    = (float*)alloc((size_t)16 * 8 * 256 * 4);

  wconv_kernel<<<dim3(16, 16, 4), 256, 0, stream>>>(Wq, Wqkvgt + (size_t)0 * 512, 512, 512,
                                                    (size_t)512 * 512, (size_t)2048 * 512);
  wconv_kernel<<<dim3(16, 16, 4), 256, 0, stream>>>(Wk, Wqkvgt + (size_t)512 * 512, 512, 512,
                                                    (size_t)512 * 512, (size_t)2048 * 512);
  wconv_kernel<<<dim3(16, 16, 4), 256, 0, stream>>>(Wv, Wqkvgt + (size_t)1024 * 512, 512, 512,
                                                    (size_t)512 * 512, (size_t)2048 * 512);
  wconv_kernel<<<dim3(16, 16, 4), 256, 0, stream>>>(Wg, Wqkvgt + (size_t)1536 * 512, 512, 512,
                                                    (size_t)512 * 512, (size_t)2048 * 512);
  wconv_kernel<<<dim3(16, 16, 4), 256, 0, stream>>>(Wo, Wot, 512, 512,
                                                    (size_t)512 * 512, (size_t)512 * 512);
  wconv_kernel<<<dim3(64, 16, 4), 256, 0, stream>>>(Wf1, Wf1t, 512, 2048,
                                                    (size_t)512 * 2048, (size_t)2048 * 512);
  wconv_kernel<<<dim3(64, 16, 4), 256, 0, stream>>>(Wfg, Wfgt, 512, 2048,
                                                    (size_t)512 * 2048, (size_t)2048 * 512);
  wconv_kernel<<<dim3(16, 64, 4), 256, 0, stream>>>(Wf2, Wf2t, 2048, 512,
                                                    (size_t)2048 * 512, (size_t)512 * 2048);
  bcat_kernel<<<dim3(32), 256, 0, stream>>>(bq, bk, bv, bg, bqkvg);

  embed_kernel<<<dim3(16384), dim3(256), 0, stream>>>(x_cgm, cgm_W, cgm_b, X, Xb);
  relmean_kernel<<<dim3(4), dim3(256), 0, stream>>>(rel_emb, RMb);

  for (int l = 0; l < Ln; ++l) {
    const size_t bof = (size_t)l * Dn;
    // fused q|k|v|gate GEMM: N=2048, K=512 (grid 512, 256x128 blocks)
    gemm256<4><<<dim3(512), 256, 0, stream>>>(Xb, Wqkvgt + (size_t)l * 2048 * 512,
                                              bqkvg + (size_t)l * 2048, QKVb, GATEb,
                                              512, 512, 16);
    attn_kernel<<<dim3(1024), dim3(256), 0, stream>>>(QKVb, RMb, CTXb);
    // Wo: N=512, 128x64 tiles (grid 512)
    mgemm_n64<3><<<dim3(512), 256, 0, stream>>>(CTXb, Wot + (size_t)l * 512 * 512,
                                                bo + bof, nullptr, ATTb, 512, 512, 512);
    ln_res1_kernel<<<dim3(2048), 256, 0, stream>>>(X, Xb, ATTb, GATEb, ln1_s + bof, ln1_b + bof);
    // fused gated FF: N=2048, K=512 (grid 1024, 256x64-pair blocks)
    ff256<<<dim3(1024), 256, 0, stream>>>(Xb, Wf1t + (size_t)l * 2048 * 512,
                                          Wfgt + (size_t)l * 2048 * 512,
                                          bf1 + (size_t)l * FFn, bfg + (size_t)l * FFn,
                                          FFBh, 512);
    // Wf2: N=512, K=2048 full-K single pass (grid 512)
    mgemm_n64<0><<<dim3(512), 256, 0, stream>>>(FFBh, Wf2t + (size_t)l * 512 * 2048,
                                                bf2 + bof, CTXo, nullptr, 2048, 2048, 512);
    ln_res2_kernel<<<dim3(2048), 256, 0, stream>>>(X, Xb, CTXo, ln2_s + bof, ln2_b + bof);
  }

  mp_part_kernel<<<dim3(16, 8), 256, 0, stream>>>(X, MPP);
  mp_comb_xo_kernel<<<dim3(32), 256, 0, stream>>>(MPP, x_other, other_W, other_b, Hb);
  f1a_kernel<<<dim3(16, 8), 256, 0, stream>>>(Hb, fW1, F1P);
  tail_kernel<<<dim3(16), 256, 0, stream>>>(F1P, fb1, fln1_s, fln1_b,
                                            fW2, fb2, fln2_s, fln2_b, fW3, fb3, out);
}

// Round 9
// 1096.130 us; speedup vs baseline: 1.3054x; 1.3054x over previous
//
#include <hip/hip_runtime.h>
#include <math.h>

constexpr int Bn = 16;
constexpr int Sn = 512;
constexpr int FCn = 24;
constexpr int FOn = 16;
constexpr int Dn = 512;
constexpr int Hn = 8;
constexpr int DKn = 64;
constexpr int FFn = 2048;
constexpr int Ln = 4;
constexpr int MAXPOSn = 512;
constexpr float EPSf = 1e-6f;

typedef __attribute__((ext_vector_type(8))) short bf16x8;   // 8 bf16 in 4 VGPRs
typedef __attribute__((ext_vector_type(4))) float floatx4;

__device__ __forceinline__ float sigmoidf_(float x) { return 1.0f / (1.0f + __expf(-x)); }

__device__ __forceinline__ unsigned short f2bf(float f) {  // RNE
  unsigned int u = __float_as_uint(f);
  u += 0x7fffu + ((u >> 16) & 1u);
  return (unsigned short)(u >> 16);
}
__device__ __forceinline__ float b2f(unsigned short b) {
  return __uint_as_float(((unsigned int)b) << 16);
}

__device__ __forceinline__ void g2l16(const void* g, void* l) {
  // async global->LDS, 16B/lane, LDS dest = wave-uniform base + lane*16
  __builtin_amdgcn_global_load_lds((const __attribute__((address_space(1))) void*)g,
                                   (__attribute__((address_space(3))) void*)l, 16, 0, 0);
}

// pair-pack bf16 store: even lane stores {self, lane^1} as one dword.
__device__ __forceinline__ void st_bf16_pair(unsigned short* dst, float v, int lane) {
  unsigned int us = f2bf(v);
  unsigned int other = (unsigned int)__shfl_xor((int)us, 1);
  if (!(lane & 1)) *(unsigned int*)dst = us | (other << 16);
}

__device__ __forceinline__ float waveReduceSum(float v) {
  #pragma unroll
  for (int off = 32; off >= 1; off >>= 1) v += __shfl_xor(v, off);
  return v;
}

__device__ __forceinline__ float blockReduceSum(float v) {
  v = waveReduceSum(v);
  __shared__ float red[8];
  const int w = threadIdx.x >> 6;
  const int nw = blockDim.x >> 6;
  if ((threadIdx.x & 63) == 0) red[w] = v;
  __syncthreads();
  float r = 0.0f;
  for (int i = 0; i < nw; ++i) r += red[i];
  __syncthreads();
  return r;
}

// ---------- weight transpose-convert: out[n][k] bf16 = in[k][n] f32 ----------
__global__ __launch_bounds__(256) void wconv_kernel(
    const float* __restrict__ in, unsigned short* __restrict__ out,
    int K, int N, size_t inStride, size_t outStride) {
  __shared__ float tile[32][33];
  in += (size_t)blockIdx.z * inStride;
  out += (size_t)blockIdx.z * outStride;
  const int k0 = blockIdx.y * 32, n0 = blockIdx.x * 32;
  const int tr = threadIdx.x >> 3;         // 0..31
  const int tc4 = (threadIdx.x & 7) * 4;   // 0..28
  float4 vv = *(const float4*)&in[(size_t)(k0 + tr) * N + n0 + tc4];
  tile[tr][tc4 + 0] = vv.x; tile[tr][tc4 + 1] = vv.y;
  tile[tr][tc4 + 2] = vv.z; tile[tr][tc4 + 3] = vv.w;
  __syncthreads();
  ushort4 o4;
  o4.x = f2bf(tile[tc4 + 0][tr]); o4.y = f2bf(tile[tc4 + 1][tr]);
  o4.z = f2bf(tile[tc4 + 2][tr]); o4.w = f2bf(tile[tc4 + 3][tr]);
  *(ushort4*)&out[(size_t)(n0 + tr) * K + k0 + tc4] = o4;
}

// fused transpose-convert for q|k|v|g: z -> (layer = z&3, part = z>>2)
// in: srcs[part] + layer*512*512 ([512][512] f32); out rows [part*512, part*512+512)
__global__ __launch_bounds__(256) void wconv4_kernel(
    const float* __restrict__ s0, const float* __restrict__ s1,
    const float* __restrict__ s2, const float* __restrict__ s3,
    unsigned short* __restrict__ out) {
  __shared__ float tile[32][33];
  const int z = blockIdx.z;
  const int l = z & 3, part = z >> 2;
  const float* in = (part == 0 ? s0 : part == 1 ? s1 : part == 2 ? s2 : s3)
                    + (size_t)l * 512 * 512;
  unsigned short* o = out + (size_t)l * 2048 * 512 + (size_t)part * 512 * 512;
  const int k0 = blockIdx.y * 32, n0 = blockIdx.x * 32;
  const int tr = threadIdx.x >> 3;
  const int tc4 = (threadIdx.x & 7) * 4;
  float4 vv = *(const float4*)&in[(size_t)(k0 + tr) * 512 + n0 + tc4];
  tile[tr][tc4 + 0] = vv.x; tile[tr][tc4 + 1] = vv.y;
  tile[tr][tc4 + 2] = vv.z; tile[tr][tc4 + 3] = vv.w;
  __syncthreads();
  ushort4 o4;
  o4.x = f2bf(tile[tc4 + 0][tr]); o4.y = f2bf(tile[tc4 + 1][tr]);
  o4.z = f2bf(tile[tc4 + 2][tr]); o4.w = f2bf(tile[tc4 + 3][tr]);
  *(ushort4*)&o[(size_t)(n0 + tr) * 512 + k0 + tc4] = o4;
}

// fused transpose-convert for f1|fg: z -> (layer = z&3, which = z>>2)
// in [512][2048] f32 -> out [2048][512] bf16
__global__ __launch_bounds__(256) void wconv2_kernel(
    const float* __restrict__ sA, const float* __restrict__ sB,
    unsigned short* __restrict__ oA, unsigned short* __restrict__ oB) {
  __shared__ float tile[32][33];
  const int z = blockIdx.z;
  const int l = z & 3, which = z >> 2;
  const float* in = (which ? sB : sA) + (size_t)l * 512 * 2048;
  unsigned short* o = (which ? oB : oA) + (size_t)l * 2048 * 512;
  const int k0 = blockIdx.y * 32, n0 = blockIdx.x * 32;
  const int tr = threadIdx.x >> 3;
  const int tc4 = (threadIdx.x & 7) * 4;
  float4 vv = *(const float4*)&in[(size_t)(k0 + tr) * 2048 + n0 + tc4];
  tile[tr][tc4 + 0] = vv.x; tile[tr][tc4 + 1] = vv.y;
  tile[tr][tc4 + 2] = vv.z; tile[tr][tc4 + 3] = vv.w;
  __syncthreads();
  ushort4 o4;
  o4.x = f2bf(tile[tc4 + 0][tr]); o4.y = f2bf(tile[tc4 + 1][tr]);
  o4.z = f2bf(tile[tc4 + 2][tr]); o4.w = f2bf(tile[tc4 + 3][tr]);
  *(ushort4*)&o[(size_t)(n0 + tr) * 512 + k0 + tc4] = o4;
}

// bias concat: [L][2048] = [bq|bk|bv|bg]
__global__ void bcat_kernel(const float* __restrict__ bq, const float* __restrict__ bk,
                            const float* __restrict__ bv, const float* __restrict__ bg,
                            float* __restrict__ out) {
  const int t = blockIdx.x * 256 + threadIdx.x;  // 8192
  const int l = t >> 11;
  const int c = t & 2047;
  float v;
  if (c < 512) v = bq[l * 512 + c];
  else if (c < 1024) v = bk[l * 512 + c - 512];
  else if (c < 1536) v = bv[l * 512 + c - 1024];
  else v = bg[l * 512 + c - 1536];
  out[t] = v;
}

// x = x_cgm @ cgm_W + cgm_b  -> fp32 X and bf16 Xb
__global__ __launch_bounds__(256) void embed_kernel(
    const float* __restrict__ xc, const float* __restrict__ W,
    const float* __restrict__ bias, float* __restrict__ x,
    unsigned short* __restrict__ xb) {
  const int idx = blockIdx.x * 256 + threadIdx.x;
  const int n = idx & (Dn - 1);
  const int m = idx >> 9;
  const float* xr = xc + m * FCn;
  float acc = bias[n];
  #pragma unroll
  for (int k = 0; k < FCn; ++k) acc = fmaf(xr[k], W[k * Dn + n], acc);
  x[idx] = acc;
  xb[idx] = f2bf(acc);
}

__global__ void relmean_kernel(const float* __restrict__ rel, float* __restrict__ rm) {
  const int p = blockIdx.x * blockDim.x + threadIdx.x;
  if (p >= 2 * MAXPOSn - 1) return;
  float s = 0.0f;
  #pragma unroll 8
  for (int d = 0; d < DKn; ++d) s += rel[p * DKn + d];
  rm[p] = s * (1.0f / DKn);
}

// ---------- bf16 MFMA GEMM (round-5/7 proven): 128x128 tile, BK=32 ----------
// Loop-carried staging pointers (+32 shorts/iter) cut per-iter address VALU.
// EPI: 0 fp32 +bias; 3 bf16 +bias (pair-packed); 4 qkvg split.
template <int EPI>
__global__ __launch_bounds__(256) void mgemm(
    const unsigned short* __restrict__ A, const unsigned short* __restrict__ Bt,
    const float* __restrict__ bias, float* __restrict__ Cf,
    unsigned short* __restrict__ Cb, unsigned short* __restrict__ Cb2,
    int Astride, int N, int Klen, int ldc, int nt) {
  __shared__ unsigned short As[128 * 32];
  __shared__ unsigned short Bs[128 * 32];
  const int t = threadIdx.x;
  const int w = t >> 6;
  const int lane = t & 63;
  const int id = blockIdx.x;
  const int xcd = id & 7;
  const int lid = id >> 3;
  const int n0 = (lid % nt) * 128;
  const int m0 = (xcd * 8 + lid / nt) * 128;
  const int wm = (w >> 1) * 64;
  const int wn = (w & 1) * 64;
  const int lr = lane & 15;
  const int lq = lane >> 4;

  floatx4 acc[4][4];
  #pragma unroll
  for (int i = 0; i < 4; ++i)
    #pragma unroll
    for (int j = 0; j < 4; ++j) acc[i][j] = (floatx4){0.f, 0.f, 0.f, 0.f};

  const int srow = lane >> 2;   // 0..15
  const int schk = (lane & 3) * 8;
  const unsigned short* pA = A + (size_t)(m0 + srow) * Astride + schk;
  const unsigned short* pB = Bt + (size_t)(n0 + srow) * Astride + schk;

  for (int k0 = 0; k0 < Klen; k0 += 32) {
    __syncthreads();
    #pragma unroll
    for (int r = 0; r < 2; ++r) {
      const int rb = (w * 2 + r) * 16;
      g2l16(pA + (size_t)rb * Astride, &As[rb * 32]);
      g2l16(pB + (size_t)rb * Astride, &Bs[rb * 32]);
    }
    pA += 32;
    pB += 32;
    __syncthreads();
    bf16x8 af[4], bf[4];
    #pragma unroll
    for (int i = 0; i < 4; ++i)
      af[i] = *(const bf16x8*)&As[(wm + i * 16 + lr) * 32 + lq * 8];
    #pragma unroll
    for (int j = 0; j < 4; ++j)
      bf[j] = *(const bf16x8*)&Bs[(wn + j * 16 + lr) * 32 + lq * 8];
    #pragma unroll
    for (int i = 0; i < 4; ++i)
      #pragma unroll
      for (int j = 0; j < 4; ++j)
        acc[i][j] = __builtin_amdgcn_mfma_f32_16x16x32_bf16(af[i], bf[j], acc[i][j], 0, 0, 0);
  }

  // C/D layout: col = lane&15, row = (lane>>4)*4 + reg
  #pragma unroll
  for (int i = 0; i < 4; ++i) {
    const int row = m0 + wm + i * 16 + lq * 4;
    #pragma unroll
    for (int j = 0; j < 4; ++j) {
      const int col = n0 + wn + j * 16 + lr;
      const int colp = col & ~1;
      #pragma unroll
      for (int r = 0; r < 4; ++r) {
        if (EPI == 0) {
          Cf[(size_t)(row + r) * ldc + col] = acc[i][j][r] + bias[col];
        } else if (EPI == 3) {
          st_bf16_pair(&Cb[(size_t)(row + r) * ldc + colp], acc[i][j][r] + bias[col], lane);
        } else if (EPI == 4) {
          const float va = acc[i][j][r] + bias[col];
          if (col < 1536)
            st_bf16_pair(&Cb[(size_t)(row + r) * 1536 + colp], va, lane);
          else
            st_bf16_pair(&Cb2[(size_t)(row + r) * 512 + (colp - 1536)], sigmoidf_(va), lane);
        }
      }
    }
  }
}

// ---------- bf16 MFMA GEMM, 128m x 64n tile (N=512: Wo, Wf2) ----------
// Grid 512 = 2 blocks/CU, full-K. EPI: 0 fp32 +bias; 3 bf16 +bias.
template <int EPI>
__global__ __launch_bounds__(256) void mgemm_n64(
    const unsigned short* __restrict__ A, const unsigned short* __restrict__ Bt,
    const float* __restrict__ bias, float* __restrict__ Cf,
    unsigned short* __restrict__ Cb, int Astride, int Klen, int ldc) {
  __shared__ unsigned short As[128 * 32];
  __shared__ unsigned short Bs[64 * 32];
  const int t = threadIdx.x;
  const int w = t >> 6;
  const int lane = t & 63;
  const int id = blockIdx.x;
  const int xcd = id & 7;
  const int lid = id >> 3;               // 0..63
  const int n0 = (lid & 7) * 64;         // 8 n-tiles
  const int m0 = (xcd * 8 + (lid >> 3)) * 128;
  const int wm = (w >> 1) * 64;
  const int wn = (w & 1) * 32;
  const int lr = lane & 15;
  const int lq = lane >> 4;

  floatx4 acc[4][2];
  #pragma unroll
  for (int i = 0; i < 4; ++i)
    #pragma unroll
    for (int j = 0; j < 2; ++j) acc[i][j] = (floatx4){0.f, 0.f, 0.f, 0.f};

  const int srow = lane >> 2;
  const int schk = (lane & 3) * 8;
  const unsigned short* pA = A + (size_t)(m0 + srow) * Astride + schk;
  const unsigned short* pB = Bt + (size_t)(n0 + w * 16 + srow) * Astride + schk;

  for (int k0 = 0; k0 < Klen; k0 += 32) {
    __syncthreads();
    #pragma unroll
    for (int r = 0; r < 2; ++r) {
      const int rb = (w * 2 + r) * 16;
      g2l16(pA + (size_t)rb * Astride, &As[rb * 32]);
    }
    g2l16(pB, &Bs[(w * 16) * 32]);
    pA += 32;
    pB += 32;
    __syncthreads();
    bf16x8 af[4], bf[2];
    #pragma unroll
    for (int i = 0; i < 4; ++i)
      af[i] = *(const bf16x8*)&As[(wm + i * 16 + lr) * 32 + lq * 8];
    #pragma unroll
    for (int j = 0; j < 2; ++j)
      bf[j] = *(const bf16x8*)&Bs[(wn + j * 16 + lr) * 32 + lq * 8];
    #pragma unroll
    for (int i = 0; i < 4; ++i)
      #pragma unroll
      for (int j = 0; j < 2; ++j)
        acc[i][j] = __builtin_amdgcn_mfma_f32_16x16x32_bf16(af[i], bf[j], acc[i][j], 0, 0, 0);
  }

  #pragma unroll
  for (int i = 0; i < 4; ++i) {
    const int row = m0 + wm + i * 16 + lq * 4;
    #pragma unroll
    for (int j = 0; j < 2; ++j) {
      const int col = n0 + wn + j * 16 + lr;
      const int colp = col & ~1;
      const float bv = bias[col];
      #pragma unroll
      for (int r = 0; r < 4; ++r) {
        if (EPI == 0) {
          Cf[(size_t)(row + r) * ldc + col] = acc[i][j][r] + bv;
        } else {
          st_bf16_pair(&Cb[(size_t)(row + r) * ldc + colp], acc[i][j][r] + bv, lane);
        }
      }
    }
  }
}

// ---------- fused gated FF (round-5/7 proven): C = (A@W1+b1)*sigmoid(A@W2+b2) ----------
__global__ __launch_bounds__(256) void ffgemm(
    const unsigned short* __restrict__ A, const unsigned short* __restrict__ B1t,
    const unsigned short* __restrict__ B2t, const float* __restrict__ b1,
    const float* __restrict__ b2, unsigned short* __restrict__ C, int K) {
  __shared__ unsigned short As[128 * 32];
  __shared__ unsigned short B1s[64 * 32];
  __shared__ unsigned short B2s[64 * 32];
  const int t = threadIdx.x;
  const int w = t >> 6;
  const int lane = t & 63;
  const int id = blockIdx.x;
  const int xcd = id & 7;
  const int lid = id >> 3;            // 0..255
  const int n0 = (lid & 31) * 64;
  const int m0 = (xcd * 8 + (lid >> 5)) * 128;
  const int wm = (w >> 1) * 64;
  const int wn = (w & 1) * 32;
  const int lr = lane & 15;
  const int lq = lane >> 4;

  floatx4 a1[4][2], a2[4][2];
  #pragma unroll
  for (int i = 0; i < 4; ++i)
    #pragma unroll
    for (int j = 0; j < 2; ++j) {
      a1[i][j] = (floatx4){0.f, 0.f, 0.f, 0.f};
      a2[i][j] = (floatx4){0.f, 0.f, 0.f, 0.f};
    }

  const int srow = lane >> 2;
  const int schk = (lane & 3) * 8;
  const unsigned short* pA0 = A + (size_t)(m0 + w * 32 + srow) * K + schk;
  const unsigned short* pA1 = A + (size_t)(m0 + w * 32 + 16 + srow) * K + schk;
  const unsigned short* pB1 = B1t + (size_t)(n0 + w * 16 + srow) * K + schk;
  const unsigned short* pB2 = B2t + (size_t)(n0 + w * 16 + srow) * K + schk;

  for (int k0 = 0; k0 < K; k0 += 32) {
    __syncthreads();
    g2l16(pA0, &As[(w * 32) * 32]);
    g2l16(pA1, &As[(w * 32 + 16) * 32]);
    g2l16(pB1, &B1s[(w * 16) * 32]);
    g2l16(pB2, &B2s[(w * 16) * 32]);
    pA0 += 32; pA1 += 32; pB1 += 32; pB2 += 32;
    __syncthreads();
    bf16x8 af[4], f1[2], f2[2];
    #pragma unroll
    for (int i = 0; i < 4; ++i)
      af[i] = *(const bf16x8*)&As[(wm + i * 16 + lr) * 32 + lq * 8];
    #pragma unroll
    for (int j = 0; j < 2; ++j) {
      f1[j] = *(const bf16x8*)&B1s[(wn + j * 16 + lr) * 32 + lq * 8];
      f2[j] = *(const bf16x8*)&B2s[(wn + j * 16 + lr) * 32 + lq * 8];
    }
    #pragma unroll
    for (int i = 0; i < 4; ++i)
      #pragma unroll
      for (int j = 0; j < 2; ++j) {
        a1[i][j] = __builtin_amdgcn_mfma_f32_16x16x32_bf16(af[i], f1[j], a1[i][j], 0, 0, 0);
        a2[i][j] = __builtin_amdgcn_mfma_f32_16x16x32_bf16(af[i], f2[j], a2[i][j], 0, 0, 0);
      }
  }

  #pragma unroll
  for (int i = 0; i < 4; ++i) {
    const int row = m0 + wm + i * 16 + lq * 4;
    #pragma unroll
    for (int j = 0; j < 2; ++j) {
      const int col = n0 + wn + j * 16 + lr;
      const int colp = col & ~1;
      const float bb1 = b1[col], bb2 = b2[col];
      #pragma unroll
      for (int r = 0; r < 4; ++r) {
        const float f = (a1[i][j][r] + bb1) * sigmoidf_(a2[i][j][r] + bb2);
        st_bf16_pair(&C[(size_t)(row + r) * 2048 + colp], f, lane);
      }
    }
  }
}

// ---------- MFMA flash attention ----------
__global__ __launch_bounds__(256) void attn_kernel(
    const unsigned short* __restrict__ qkv, const float* __restrict__ rm,
    unsigned short* __restrict__ ctx) {
  __shared__ unsigned short Ks[64 * 72];
  __shared__ unsigned short Vt[64 * 72];
  __shared__ unsigned short Pw[4][16 * 72];
  __shared__ float rml[576];
  const int t = threadIdx.x;
  const int w = t >> 6;
  const int lane = t & 63;
  const int lr = lane & 15;
  const int lq = lane >> 4;
  const int bid = blockIdx.x;
  const int b = bid & 15;
  const int h = (bid >> 4) & 7;
  const int qt = bid >> 7;
  const int q0 = qt * 64;
  const size_t rowb = (size_t)b * Sn * 1536;

  for (int i = t; i < 576; i += 256) rml[i] = rm[q0 + i];

  bf16x8 aq0, aq1;
  {
    const unsigned short* qp = &qkv[rowb + (size_t)(q0 + w * 16 + lr) * 1536 + h * 64 + lq * 8];
    aq0 = *(const bf16x8*)qp;
    aq1 = *(const bf16x8*)(qp + 32);
  }

  floatx4 o_acc[4];
  #pragma unroll
  for (int i = 0; i < 4; ++i) o_acc[i] = (floatx4){0.f, 0.f, 0.f, 0.f};
  float m_old[4] = {-1e30f, -1e30f, -1e30f, -1e30f};
  float l_sum[4] = {0.f, 0.f, 0.f, 0.f};

  const int skey = t >> 2;
  const int schk = (t & 3) * 16;
  const int vkp = t >> 4;
  const int vd4 = (t & 15) * 4;

  for (int kc = 0; kc < 8; ++kc) {
    __syncthreads();
    {
      const unsigned short* gk = &qkv[rowb + (size_t)(kc * 64 + skey) * 1536 + 512 + h * 64 + schk];
      *(bf16x8*)&Ks[skey * 72 + schk] = *(const bf16x8*)gk;
      *(bf16x8*)&Ks[skey * 72 + schk + 8] = *(const bf16x8*)(gk + 8);
    }
    #pragma unroll
    for (int pass = 0; pass < 2; ++pass) {
      const int kp = vkp + pass * 16;
      const unsigned short* gv = &qkv[rowb + (size_t)(kc * 64 + kp * 2) * 1536 + 1024 + h * 64 + vd4];
      ushort4 v0 = *(const ushort4*)gv;
      ushort4 v1 = *(const ushort4*)(gv + 1536);
      *(ushort2*)&Vt[(vd4 + 0) * 72 + kp * 2] = make_ushort2(v0.x, v1.x);
      *(ushort2*)&Vt[(vd4 + 1) * 72 + kp * 2] = make_ushort2(v0.y, v1.y);
      *(ushort2*)&Vt[(vd4 + 2) * 72 + kp * 2] = make_ushort2(v0.z, v1.z);
      *(ushort2*)&Vt[(vd4 + 3) * 72 + kp * 2] = make_ushort2(v0.w, v1.w);
    }
    __syncthreads();

    floatx4 s_acc[4];
    #pragma unroll
    for (int j = 0; j < 4; ++j) {
      bf16x8 b0 = *(const bf16x8*)&Ks[(j * 16 + lr) * 72 + lq * 8];
      bf16x8 b1 = *(const bf16x8*)&Ks[(j * 16 + lr) * 72 + 32 + lq * 8];
      s_acc[j] = __builtin_amdgcn_mfma_f32_16x16x32_bf16(aq0, b0, (floatx4){0.f, 0.f, 0.f, 0.f}, 0, 0, 0);
      s_acc[j] = __builtin_amdgcn_mfma_f32_16x16x32_bf16(aq1, b1, s_acc[j], 0, 0, 0);
    }

    float mloc[4] = {-1e30f, -1e30f, -1e30f, -1e30f};
    #pragma unroll
    for (int j = 0; j < 4; ++j) {
      const int key = kc * 64 + j * 16 + lr;
      #pragma unroll
      for (int r = 0; r < 4; ++r) {
        const float sv = s_acc[j][r] * 0.125f + rml[(w * 16 + lq * 4 + r) + 511 - key];
        s_acc[j][r] = sv;
        mloc[r] = fmaxf(mloc[r], sv);
      }
    }
    #pragma unroll
    for (int off = 1; off <= 8; off <<= 1)
      #pragma unroll
      for (int r = 0; r < 4; ++r) mloc[r] = fmaxf(mloc[r], __shfl_xor(mloc[r], off));

    float alpha[4], rsum[4];
    #pragma unroll
    for (int r = 0; r < 4; ++r) {
      const float mnew = fmaxf(m_old[r], mloc[r]);
      alpha[r] = __expf(m_old[r] - mnew);
      m_old[r] = mnew;
      rsum[r] = 0.f;
    }
    #pragma unroll
    for (int j = 0; j < 4; ++j)
      #pragma unroll
      for (int r = 0; r < 4; ++r) {
        const float p = __expf(s_acc[j][r] - m_old[r]);
        rsum[r] += p;
        Pw[w][(lq * 4 + r) * 72 + j * 16 + lr] = f2bf(p);
      }
    #pragma unroll
    for (int off = 1; off <= 8; off <<= 1)
      #pragma unroll
      for (int r = 0; r < 4; ++r) rsum[r] += __shfl_xor(rsum[r], off);
    #pragma unroll
    for (int r = 0; r < 4; ++r) l_sum[r] = l_sum[r] * alpha[r] + rsum[r];
    #pragma unroll
    for (int i = 0; i < 4; ++i)
      #pragma unroll
      for (int r = 0; r < 4; ++r) o_acc[i][r] *= alpha[r];

    bf16x8 ap0 = *(const bf16x8*)&Pw[w][lr * 72 + lq * 8];
    bf16x8 ap1 = *(const bf16x8*)&Pw[w][lr * 72 + 32 + lq * 8];
    #pragma unroll
    for (int i = 0; i < 4; ++i) {
      bf16x8 v0 = *(const bf16x8*)&Vt[(i * 16 + lr) * 72 + lq * 8];
      bf16x8 v1 = *(const bf16x8*)&Vt[(i * 16 + lr) * 72 + 32 + lq * 8];
      o_acc[i] = __builtin_amdgcn_mfma_f32_16x16x32_bf16(ap0, v0, o_acc[i], 0, 0, 0);
      o_acc[i] = __builtin_amdgcn_mfma_f32_16x16x32_bf16(ap1, v1, o_acc[i], 0, 0, 0);
    }
  }

  float rinv[4];
  #pragma unroll
  for (int r = 0; r < 4; ++r) rinv[r] = 1.0f / l_sum[r];
  #pragma unroll
  for (int i = 0; i < 4; ++i)
    #pragma unroll
    for (int r = 0; r < 4; ++r) {
      const int q = q0 + w * 16 + lq * 4 + r;
      ctx[((size_t)(b * Sn + q)) * Dn + h * 64 + i * 16 + lr] = f2bf(o_acc[i][r] * rinv[r]);
    }
}

// ---------- wave-per-row LN (no barriers): 4 rows/block ----------
__global__ __launch_bounds__(256) void ln_res1_kernel(
    float* __restrict__ x, unsigned short* __restrict__ xb,
    const unsigned short* __restrict__ att, const unsigned short* __restrict__ gate,
    const float* __restrict__ s, const float* __restrict__ bsh) {
  const int w = threadIdx.x >> 6, lane = threadIdx.x & 63;
  const int row = blockIdx.x * 4 + w;
  const size_t base = (size_t)row * Dn;
  const int c = lane * 4;
  float4 xv0 = *(const float4*)&x[base + c];
  float4 xv1 = *(const float4*)&x[base + c + 256];
  ushort4 a0 = *(const ushort4*)&att[base + c];
  ushort4 a1 = *(const ushort4*)&att[base + c + 256];
  ushort4 g0 = *(const ushort4*)&gate[base + c];
  ushort4 g1 = *(const ushort4*)&gate[base + c + 256];
  float y[8];
  y[0] = xv0.x + b2f(a0.x) * b2f(g0.x);
  y[1] = xv0.y + b2f(a0.y) * b2f(g0.y);
  y[2] = xv0.z + b2f(a0.z) * b2f(g0.z);
  y[3] = xv0.w + b2f(a0.w) * b2f(g0.w);
  y[4] = xv1.x + b2f(a1.x) * b2f(g1.x);
  y[5] = xv1.y + b2f(a1.y) * b2f(g1.y);
  y[6] = xv1.z + b2f(a1.z) * b2f(g1.z);
  y[7] = xv1.w + b2f(a1.w) * b2f(g1.w);
  float sum = 0.f;
  #pragma unroll
  for (int i = 0; i < 8; ++i) sum += y[i];
  const float mu = waveReduceSum(sum) * (1.0f / Dn);
  float vs = 0.f;
  #pragma unroll
  for (int i = 0; i < 8; ++i) { y[i] -= mu; vs += y[i] * y[i]; }
  const float rstd = rsqrtf(waveReduceSum(vs) * (1.0f / Dn) + EPSf);
  float4 s0 = *(const float4*)&s[c], s1 = *(const float4*)&s[c + 256];
  float4 b0 = *(const float4*)&bsh[c], b1 = *(const float4*)&bsh[c + 256];
  float4 o0, o1;
  o0.x = y[0] * rstd * s0.x + b0.x; o0.y = y[1] * rstd * s0.y + b0.y;
  o0.z = y[2] * rstd * s0.z + b0.z; o0.w = y[3] * rstd * s0.w + b0.w;
  o1.x = y[4] * rstd * s1.x + b1.x; o1.y = y[5] * rstd * s1.y + b1.y;
  o1.z = y[6] * rstd * s1.z + b1.z; o1.w = y[7] * rstd * s1.w + b1.w;
  *(float4*)&x[base + c] = o0;
  *(float4*)&x[base + c + 256] = o1;
  ushort4 ob0, ob1;
  ob0.x = f2bf(o0.x); ob0.y = f2bf(o0.y); ob0.z = f2bf(o0.z); ob0.w = f2bf(o0.w);
  ob1.x = f2bf(o1.x); ob1.y = f2bf(o1.y); ob1.z = f2bf(o1.z); ob1.w = f2bf(o1.w);
  *(ushort4*)&xb[base + c] = ob0;
  *(ushort4*)&xb[base + c + 256] = ob1;
}

__global__ __launch_bounds__(256) void ln_res2_kernel(
    float* __restrict__ x, unsigned short* __restrict__ xb,
    const float* __restrict__ add, const float* __restrict__ s,
    const float* __restrict__ bsh) {
  const int w = threadIdx.x >> 6, lane = threadIdx.x & 63;
  const int row = blockIdx.x * 4 + w;
  const size_t base = (size_t)row * Dn;
  const int c = lane * 4;
  float4 xv0 = *(const float4*)&x[base + c];
  float4 xv1 = *(const float4*)&x[base + c + 256];
  float4 a0 = *(const float4*)&add[base + c];
  float4 a1 = *(const float4*)&add[base + c + 256];
  float y[8] = {xv0.x + a0.x, xv0.y + a0.y, xv0.z + a0.z, xv0.w + a0.w,
                xv1.x + a1.x, xv1.y + a1.y, xv1.z + a1.z, xv1.w + a1.w};
  float sum = 0.f;
  #pragma unroll
  for (int i = 0; i < 8; ++i) sum += y[i];
  const float mu = waveReduceSum(sum) * (1.0f / Dn);
  float vs = 0.f;
  #pragma unroll
  for (int i = 0; i < 8; ++i) { y[i] -= mu; vs += y[i] * y[i]; }
  const float rstd = rsqrtf(waveReduceSum(vs) * (1.0f / Dn) + EPSf);
  float4 s0 = *(const float4*)&s[c], s1 = *(const float4*)&s[c + 256];
  float4 b0 = *(const float4*)&bsh[c], b1 = *(const float4*)&bsh[c + 256];
  float4 o0, o1;
  o0.x = y[0] * rstd * s0.x + b0.x; o0.y = y[1] * rstd * s0.y + b0.y;
  o0.z = y[2] * rstd * s0.z + b0.z; o0.w = y[3] * rstd * s0.w + b0.w;
  o1.x = y[4] * rstd * s1.x + b1.x; o1.y = y[5] * rstd * s1.y + b1.y;
  o1.z = y[6] * rstd * s1.z + b1.z; o1.w = y[7] * rstd * s1.w + b1.w;
  *(float4*)&x[base + c] = o0;
  *(float4*)&x[base + c + 256] = o1;
  ushort4 ob0, ob1;
  ob0.x = f2bf(o0.x); ob0.y = f2bf(o0.y); ob0.z = f2bf(o0.z); ob0.w = f2bf(o0.w);
  ob1.x = f2bf(o1.x); ob1.y = f2bf(o1.y); ob1.z = f2bf(o1.z); ob1.w = f2bf(o1.w);
  *(ushort4*)&xb[base + c] = ob0;
  *(ushort4*)&xb[base + c + 256] = ob1;
}

// meanpool partial: block (b, sc) sums 64 rows -> part[b][sc][512]
__global__ __launch_bounds__(256) void mp_part_kernel(const float* __restrict__ x,
                                                      float* __restrict__ part) {
  const int b = blockIdx.x, sc = blockIdx.y;
  const int t = threadIdx.x;
  float s0 = 0.f, s1 = 0.f;
  for (int si = sc * 64; si < sc * 64 + 64; ++si) {
    s0 += x[((size_t)(b * Sn + si)) * Dn + t];
    s1 += x[((size_t)(b * Sn + si)) * Dn + t + 256];
  }
  part[(size_t)(b * 8 + sc) * 512 + t] = s0;
  part[(size_t)(b * 8 + sc) * 512 + t + 256] = s1;
}

// combine + xo: h[b][0:512] = mean, h[b][512:1024] = x_other@W+b
__global__ __launch_bounds__(256) void mp_comb_xo_kernel(
    const float* __restrict__ part, const float* __restrict__ xo,
    const float* __restrict__ oW, const float* __restrict__ ob,
    float* __restrict__ h) {
  const int idx = blockIdx.x * 256 + threadIdx.x;  // 8192
  const int b = idx >> 9, d = idx & 511;
  float s = 0.f;
  #pragma unroll
  for (int i = 0; i < 8; ++i) s += part[(size_t)(b * 8 + i) * 512 + d];
  h[b * 1024 + d] = s * (1.0f / Sn);
  float acc = ob[d];
  #pragma unroll
  for (int k = 0; k < FOn; ++k) acc = fmaf(xo[b * FOn + k], oW[k * Dn + d], acc);
  h[b * 1024 + 512 + d] = acc;
}

// f1 phase A: part[b][kq][n] = sum_{k in slice} h[b][k] * W[k][n]   (grid 16x8)
__global__ __launch_bounds__(256) void f1a_kernel(
    const float* __restrict__ h, const float* __restrict__ W,
    float* __restrict__ part) {
  const int b = blockIdx.x, kq = blockIdx.y;
  const int n = threadIdx.x;  // 256
  const float* hr = h + b * 1024 + kq * 128;
  const float* Wp = W + (size_t)(kq * 128) * 256 + n;
  float acc = 0.f;
  #pragma unroll 8
  for (int k = 0; k < 128; ++k) acc = fmaf(hr[k], Wp[(size_t)k * 256], acc);
  part[(size_t)(b * 8 + kq) * 256 + n] = acc;
}

// tail: f1b (sum partials + LN256 + relu) -> f2 (GEMV + LN128 + relu) -> f3 (dot)
__global__ __launch_bounds__(256) void tail_kernel(
    const float* __restrict__ part, const float* __restrict__ fb1,
    const float* __restrict__ fln1_s, const float* __restrict__ fln1_b,
    const float* __restrict__ fW2, const float* __restrict__ fb2,
    const float* __restrict__ fln2_s, const float* __restrict__ fln2_b,
    const float* __restrict__ fW3, const float* __restrict__ fb3,
    float* __restrict__ out) {
  __shared__ float h1[256];
  const int b = blockIdx.x;
  const int t = threadIdx.x;  // 256
  float acc = fb1[t];
  #pragma unroll
  for (int i = 0; i < 8; ++i) acc += part[(size_t)(b * 8 + i) * 256 + t];
  float mu = blockReduceSum(acc) * (1.0f / 256.0f);
  float d = acc - mu;
  float var = blockReduceSum(d * d) * (1.0f / 256.0f);
  h1[t] = fmaxf(d * rsqrtf(var + EPSf) * fln1_s[t] + fln1_b[t], 0.0f);
  __syncthreads();
  float acc2 = 0.f;
  if (t < 128) {
    #pragma unroll 8
    for (int k = 0; k < 256; ++k) acc2 = fmaf(h1[k], fW2[k * 128 + t], acc2);
    acc2 += fb2[t];
  }
  mu = blockReduceSum(t < 128 ? acc2 : 0.f) * (1.0f / 128.0f);
  d = (t < 128) ? acc2 - mu : 0.f;
  var = blockReduceSum(d * d) * (1.0f / 128.0f);
  float v = 0.f;
  if (t < 128) {
    const float h2v = fmaxf(d * rsqrtf(var + EPSf) * fln2_s[t] + fln2_b[t], 0.0f);
    v = h2v * fW3[t];
  }
  v = blockReduceSum(v);
  if (t == 0) out[b] = v + fb3[0];
}

extern "C" void kernel_launch(void* const* d_in, const int* in_sizes, int n_in,
                              void* d_out, int out_size, void* d_ws, size_t ws_size,
                              hipStream_t stream) {
  (void)in_sizes; (void)n_in; (void)out_size; (void)ws_size;
  const float* x_cgm  = (const float*)d_in[0];
  const float* x_other= (const float*)d_in[1];
  const float* cgm_W  = (const float*)d_in[2];
  const float* cgm_b  = (const float*)d_in[3];
  const float* rel_emb= (const float*)d_in[4];
  const float* Wq = (const float*)d_in[5];
  const float* bq = (const float*)d_in[6];
  const float* Wk = (const float*)d_in[7];
  const float* bk = (const float*)d_in[8];
  const float* Wv = (const float*)d_in[9];
  const float* bv = (const float*)d_in[10];
  const float* Wo = (const float*)d_in[11];
  const float* bo = (const float*)d_in[12];
  const float* Wg = (const float*)d_in[13];
  const float* bg = (const float*)d_in[14];
  const float* Wf1 = (const float*)d_in[15];
  const float* bf1 = (const float*)d_in[16];
  const float* Wfg = (const float*)d_in[17];
  const float* bfg = (const float*)d_in[18];
  const float* Wf2 = (const float*)d_in[19];
  const float* bf2 = (const float*)d_in[20];
  const float* ln1_s = (const float*)d_in[21];
  const float* ln1_b = (const float*)d_in[22];
  const float* ln2_s = (const float*)d_in[23];
  const float* ln2_b = (const float*)d_in[24];
  const float* other_W = (const float*)d_in[25];
  const float* other_b = (const float*)d_in[26];
  const float* fW1 = (const float*)d_in[27];
  const float* fb1 = (const float*)d_in[28];
  const float* fln1_s = (const float*)d_in[29];
  const float* fln1_b = (const float*)d_in[30];
  const float* fW2 = (const float*)d_in[31];
  const float* fb2 = (const float*)d_in[32];
  const float* fln2_s = (const float*)d_in[33];
  const float* fln2_b = (const float*)d_in[34];
  const float* fW3 = (const float*)d_in[35];
  const float* fb3 = (const float*)d_in[36];
  float* out = (float*)d_out;

  char* p = (char*)d_ws;
  auto alloc = [&](size_t bytes) { char* r = p; p += (bytes + 255) & ~(size_t)255; return r; };
  float*          X      = (float*)alloc((size_t)8192 * 512 * 4);
  unsigned short* Xb     = (unsigned short*)alloc((size_t)8192 * 512 * 2);
  unsigned short* QKVb   = (unsigned short*)alloc((size_t)8192 * 1536 * 2);  // also CTXo f32
  unsigned short* CTXb   = (unsigned short*)alloc((size_t)8192 * 512 * 2);
  char*           R      = alloc((size_t)8192 * 2048 * 2);  // ATTb|GATEb bf16 / FFBh overlay
  unsigned short* ATTb   = (unsigned short*)R;
  unsigned short* GATEb  = (unsigned short*)(R + (size_t)8192 * 512 * 2);
  unsigned short* FFBh   = (unsigned short*)R;               // [8192][2048] bf16
  float*          CTXo   = (float*)QKVb;
  unsigned short* Wqkvgt = (unsigned short*)alloc((size_t)4 * 2048 * 512 * 2);
  unsigned short* Wot    = (unsigned short*)alloc((size_t)4 * 512 * 512 * 2);
  unsigned short* Wf1t   = (unsigned short*)alloc((size_t)4 * 2048 * 512 * 2);
  unsigned short* Wfgt   = (unsigned short*)alloc((size_t)4 * 2048 * 512 * 2);
  unsigned short* Wf2t   = (unsigned short*)alloc((size_t)4 * 512 * 2048 * 2);
  float*          bqkvg  = (float*)alloc((size_t)4 * 2048 * 4);
  float*          RMb    = (float*)alloc(1024 * 4);
  float*          Hb     = (float*)alloc(16 * 1024 * 4);
  float*          MPP    = (float*)alloc((size_t)16 * 8 * 512 * 4);
  float*          F1P    = (float*)alloc((size_t)16 * 8 * 256 * 4);

  // fused weight conversion: 4 launches instead of 8
  wconv4_kernel<<<dim3(16, 16, 16), 256, 0, stream>>>(Wq, Wk, Wv, Wg, Wqkvgt);
  wconv2_kernel<<<dim3(64, 16, 8), 256, 0, stream>>>(Wf1, Wfg, Wf1t, Wfgt);
  wconv_kernel<<<dim3(16, 16, 4), 256, 0, stream>>>(Wo, Wot, 512, 512,
                                                    (size_t)512 * 512, (size_t)512 * 512);
  wconv_kernel<<<dim3(16, 64, 4), 256, 0, stream>>>(Wf2, Wf2t, 2048, 512,
                                                    (size_t)2048 * 512, (size_t)512 * 2048);
  bcat_kernel<<<dim3(32), 256, 0, stream>>>(bq, bk, bv, bg, bqkvg);

  embed_kernel<<<dim3(16384), dim3(256), 0, stream>>>(x_cgm, cgm_W, cgm_b, X, Xb);
  relmean_kernel<<<dim3(4), dim3(256), 0, stream>>>(rel_emb, RMb);

  for (int l = 0; l < Ln; ++l) {
    const size_t bof = (size_t)l * Dn;
    // fused q|k|v|gate GEMM: N=2048, K=512 (grid 1024, nt=16)
    mgemm<4><<<dim3(1024), 256, 0, stream>>>(Xb, Wqkvgt + (size_t)l * 2048 * 512,
                                             bqkvg + (size_t)l * 2048, nullptr, QKVb, GATEb,
                                             512, 2048, 512, 0, 16);
    attn_kernel<<<dim3(1024), dim3(256), 0, stream>>>(QKVb, RMb, CTXb);
    // Wo: N=512, 128x64 tiles (grid 512, 2 blocks/CU)
    mgemm_n64<3><<<dim3(512), 256, 0, stream>>>(CTXb, Wot + (size_t)l * 512 * 512,
                                                bo + bof, nullptr, ATTb, 512, 512, 512);
    ln_res1_kernel<<<dim3(2048), 256, 0, stream>>>(X, Xb, ATTb, GATEb, ln1_s + bof, ln1_b + bof);
    // fused gated FF: N=2048, K=512 (grid 2048)
    ffgemm<<<dim3(2048), 256, 0, stream>>>(Xb, Wf1t + (size_t)l * 2048 * 512,
                                           Wfgt + (size_t)l * 2048 * 512,
                                           bf1 + (size_t)l * FFn, bfg + (size_t)l * FFn,
                                           FFBh, 512);
    // Wf2: N=512, K=2048 full-K single pass (grid 512)
    mgemm_n64<0><<<dim3(512), 256, 0, stream>>>(FFBh, Wf2t + (size_t)l * 512 * 2048,
                                                bf2 + bof, CTXo, nullptr, 2048, 2048, 512);
    ln_res2_kernel<<<dim3(2048), 256, 0, stream>>>(X, Xb, CTXo, ln2_s + bof, ln2_b + bof);
  }

  mp_part_kernel<<<dim3(16, 8), 256, 0, stream>>>(X, MPP);
  mp_comb_xo_kernel<<<dim3(32), 256, 0, stream>>>(MPP, x_other, other_W, other_b, Hb);
  f1a_kernel<<<dim3(16, 8), 256, 0, stream>>>(Hb, fW1, F1P);
  tail_kernel<<<dim3(16), 256, 0, stream>>>(F1P, fb1, fln1_s, fln1_b,
                                            fW2, fb2, fln2_s, fln2_b, fW3, fb3, out);
}